// Round 3
// baseline (476.114 us; speedup 1.0000x reference)
//
#include <hip/hip_runtime.h>
#include <math.h>
#include <stdint.h>

// GAT 2-layer: N=50000 nodes, E=800000 edges (+N self loops)
// L1: 512 -> 4 heads x 64 (bf16 MFMA GEMM reading fp32 x directly, cvt fused
//     into A-staging; att1 fused in epilogue), ELU.
// L2: 256 -> 1 head x 40 (att2 fused in gemm2), log_softmax.
// Softmax WITHOUT max-shift (logits ~N(0,1), clamped at 80): per-edge exp in
// k_fill (L1) / k_pre2 (L2); agg kernels consume wave-uniform scalar streams.
//
// R3: gemm1 tile 128x128 -> 64x128 (1564 blocks, 6.1/CU) to raise TLP.
// Rationale: __syncthreads drains vmcnt(0) every step (no cross-step hiding is
// possible in a 1-barrier/step structure), so the kernel is latency-bound and
// the only lever is resident-wave count: 12 -> ~16-24 waves/CU.

typedef short bf16x8 __attribute__((ext_vector_type(8)));
typedef float f32x4  __attribute__((ext_vector_type(4)));

static __device__ __forceinline__ float leaky(float x){ return x > 0.f ? x : 0.2f*x; }
static __device__ __forceinline__ unsigned short f2bf(float f){
  uint32_t u = __float_as_uint(f);
  uint32_t r = u + 0x7fffu + ((u >> 16) & 1u);   // RNE
  return (unsigned short)(r >> 16);
}
static __device__ __forceinline__ float bf2f(unsigned short u){
  return __uint_as_float(((uint32_t)u) << 16);
}

// ---------------- convert+transpose W1 -> w1t bf16; also zero deg ----------------
__global__ void k_cvt_w(const float* __restrict__ W, unsigned short* __restrict__ wt,
                        int* __restrict__ deg, int n){
  int i = blockIdx.x*blockDim.x + threadIdx.x;   // 0..131071
  if (i < n) deg[i] = 0;
  if (i >= 512*256) return;
  int k = i >> 8, c = i & 255;
  wt[c*512 + k] = f2bf(W[i]);
}

// ---------------- count in-degree (incl self loops) ----------------
__global__ void k_count(const int* __restrict__ ei, int E, int n, int* __restrict__ deg){
  int i = blockIdx.x*blockDim.x + threadIdx.x;
  int tot = E + n;
  if (i >= tot) return;
  int dst = (i < E) ? ei[E + i] : (i - E);
  atomicAdd(&deg[dst], 1);
}

// ---------------- multi-block exclusive scan: deg[n] -> rowstart[0..n] ----------------
__global__ __launch_bounds__(256) void k_scan_a(const int* __restrict__ deg,
    int* __restrict__ rowstart, int* __restrict__ bsum, int n){
  __shared__ int sm[256];
  int b = blockIdx.x, t = threadIdx.x;
  int i = b*256 + t;
  int v = (i < n) ? deg[i] : 0;
  sm[t] = v;
  __syncthreads();
  for (int off=1; off<256; off<<=1){
    int u = (t >= off) ? sm[t-off] : 0;
    __syncthreads();
    sm[t] += u;
    __syncthreads();
  }
  if (i < n) rowstart[i+1] = sm[t];
  if (t == 255) bsum[b] = sm[255];
}
__global__ __launch_bounds__(256) void k_scan_b(int* __restrict__ bsum, int nb){
  __shared__ int sm[256];
  int t = threadIdx.x;
  int v = (t < nb) ? bsum[t] : 0;
  sm[t] = v;
  __syncthreads();
  for (int off=1; off<256; off<<=1){
    int u = (t >= off) ? sm[t-off] : 0;
    __syncthreads();
    sm[t] += u;
    __syncthreads();
  }
  if (t < nb) bsum[t] = sm[t] - v;   // exclusive prefix
}
__global__ __launch_bounds__(256) void k_scan_c(int* __restrict__ rowstart,
    const int* __restrict__ bsum, int* __restrict__ cur, int n){
  int b = blockIdx.x, t = threadIdx.x;
  int i = b*256 + t;
  if (i < n){ rowstart[i+1] += bsum[b]; cur[i] = 0; }
  if (i == 0) rowstart[0] = 0;
}

// ---------------- GEMM1 (bf16 MFMA, fp32 A with fused cvt) + fused att1 ----------
// Tile 64 rows x 128 cols, 4 waves: wave w -> rows wx*32 (wx=w&1), cols wy*64
// (wy=w>>1). Per step: A 64x32 fp32->bf16 (1 chunk/thread), B 128x32 bf16 via
// global_load_lds; 8 MFMA/wave; ONE __syncthreads per step.
__global__ __launch_bounds__(256, 4) void k_gemm1_mfma(const float* __restrict__ X,
                                                    const unsigned short* __restrict__ BT,
                                                    const float* __restrict__ SW,
                                                    const float* __restrict__ DW,
                                                    unsigned short* __restrict__ Cb,
                                                    float* __restrict__ as1,
                                                    float* __restrict__ ad1, int M){
  __shared__ __align__(16) unsigned short lA[2][2048];  // 2 x 4 KB (64 rows x 32 k bf16)
  __shared__ __align__(16) unsigned short lB[2][4096];  // 2 x 8 KB (128 cols x 32 k)
  const int t = threadIdx.x;
  const int lane = t & 63, w = t >> 6;
  const int wx = w & 1, wy = w >> 1;
  const int row0 = blockIdx.x * 64, col0 = blockIdx.y * 128;

  f32x4 acc[2][4];
  #pragma unroll
  for (int i=0;i<2;i++)
    #pragma unroll
    for (int j=0;j<4;j++)
      #pragma unroll
      for (int r=0;r<4;r++) acc[i][j][r] = 0.f;

  // A staging: thread t covers (row rA = t&63, chunk kqA = t>>6), 8 floats
  const int rA = t & 63, kqA = t >> 6;
  const float* xA = X + (size_t)min(row0 + rA, M-1)*512 + kqA*8;

  // B staging: two slots per thread (same as 128-tile version)
  const int c0 = t, c1 = t + 256;
  const int rB0 = c0 & 127, kqB0 = c0 >> 7;   // {0,1}
  const int rB1 = c1 & 127, kqB1 = c1 >> 7;   // {2,3}
  const unsigned short* bB0 = BT + (size_t)(col0 + rB0)*512 + kqB0*8;
  const unsigned short* bB1 = BT + (size_t)(col0 + rB1)*512 + kqB1*8;

  const int kq = lane >> 4, li = lane & 15;

#define ISSUE_B(NXT, KTB) do{ \
  __builtin_amdgcn_global_load_lds((const __attribute__((address_space(1))) void*)(bB0 + (KTB)), \
      (__attribute__((address_space(3))) void*)&lB[NXT][c0*8], 16, 0, 0); \
  __builtin_amdgcn_global_load_lds((const __attribute__((address_space(1))) void*)(bB1 + (KTB)), \
      (__attribute__((address_space(3))) void*)&lB[NXT][c1*8], 16, 0, 0); }while(0)

#define CVT_WRITE(NXT, S0,S1) do{ \
  bf16x8 p0; \
  p0[0]=(short)f2bf(S0.x); p0[1]=(short)f2bf(S0.y); p0[2]=(short)f2bf(S0.z); p0[3]=(short)f2bf(S0.w); \
  p0[4]=(short)f2bf(S1.x); p0[5]=(short)f2bf(S1.y); p0[6]=(short)f2bf(S1.z); p0[7]=(short)f2bf(S1.w); \
  *(bf16x8*)&lA[NXT][t*8] = p0; }while(0)

#define STEP(T, CUR) do{ \
  float4 n0, n1; \
  if ((T) < 15){ \
    const int ktn = ((T)+1)*32; \
    n0 = *(const float4*)(xA + ktn); \
    n1 = *(const float4*)(xA + ktn + 4); \
    ISSUE_B((CUR)^1, ktn); \
  } \
  bf16x8 af[2], bfr[4]; \
  _Pragma("unroll") \
  for (int i=0;i<2;i++) \
    af[i]  = *(const bf16x8*)&lA[CUR][(kq*64 + wx*32 + i*16 + li)*8]; \
  _Pragma("unroll") \
  for (int j=0;j<4;j++) \
    bfr[j] = *(const bf16x8*)&lB[CUR][(kq*128 + wy*64 + j*16 + li)*8]; \
  _Pragma("unroll") \
  for (int i=0;i<2;i++) \
    _Pragma("unroll") \
    for (int j=0;j<4;j++) \
      acc[i][j] = __builtin_amdgcn_mfma_f32_16x16x32_bf16(af[i], bfr[j], acc[i][j], 0, 0, 0); \
  if ((T) < 15){ \
    CVT_WRITE((CUR)^1, n0, n1); \
    __syncthreads(); \
  } \
}while(0)

  // ---- prologue: stage tile 0 into buf 0
  {
    float4 a0 = *(const float4*)(xA);
    float4 a1 = *(const float4*)(xA + 4);
    ISSUE_B(0, 0);
    CVT_WRITE(0, a0, a1);
    __syncthreads();
  }

  // ---- 16 K-steps, fully unrolled, buffers ping-pong at compile time
  #pragma unroll
  for (int tt = 0; tt < 8; ++tt){
    STEP(2*tt,   (0));
    STEP(2*tt+1, (1));
  }

#undef STEP
#undef CVT_WRITE
#undef ISSUE_B

  // epilogue 1: C store. C/D map col=lane&15, row=(lane>>4)*4+reg
  #pragma unroll
  for (int i=0;i<2;i++){
    #pragma unroll
    for (int r=0;r<4;r++){
      int row = row0 + wx*32 + i*16 + kq*4 + r;
      if (row < M){
        #pragma unroll
        for (int j=0;j<4;j++)
          Cb[(size_t)row*256 + col0 + wy*64 + j*16 + li] = f2bf(acc[i][j][r]);
      }
    }
  }

  // epilogue 2: fused att1 dots for head hw (this wave's 64-col span)
  const int hw = (int)blockIdx.y*2 + wy;
  float sv[4], dv[4];
  #pragma unroll
  for (int j=0;j<4;j++){
    sv[j] = SW[hw*64 + j*16 + li];
    dv[j] = DW[hw*64 + j*16 + li];
  }
  #pragma unroll
  for (int i=0;i<2;i++){
    #pragma unroll
    for (int r=0;r<4;r++){
      float ps = acc[i][0][r]*sv[0] + acc[i][1][r]*sv[1] + acc[i][2][r]*sv[2] + acc[i][3][r]*sv[3];
      float pd = acc[i][0][r]*dv[0] + acc[i][1][r]*dv[1] + acc[i][2][r]*dv[2] + acc[i][3][r]*dv[3];
      #pragma unroll
      for (int o=1;o<16;o<<=1){ ps += __shfl_xor(ps,o); pd += __shfl_xor(pd,o); }
      int row = row0 + wx*32 + i*16 + kq*4 + r;
      if (li == 0 && row < M){
        as1[row*4 + hw] = ps;
        ad1[row*4 + hw] = pd;
      }
    }
  }
}

// ---------------- scatter edges into CSR + compute per-edge ex (4 heads) ----------
__global__ void k_fill(const int* __restrict__ ei, int E, int n,
                       const int* __restrict__ rowstart, int* __restrict__ cur,
                       int* __restrict__ csr,
                       const float* __restrict__ as1, const float* __restrict__ ad1,
                       float* __restrict__ exbuf){
  int i = blockIdx.x*blockDim.x + threadIdx.x;
  int tot = E + n;
  if (i >= tot) return;
  int src, dst;
  if (i < E){ src = ei[i]; dst = ei[E+i]; } else { src = i - E; dst = src; }
  int pos = atomicAdd(&cur[dst], 1);
  int slot = rowstart[dst] + pos;
  csr[slot] = src;
  float4 a = *(const float4*)(as1 + (size_t)src*4);
  float4 d = *(const float4*)(ad1 + (size_t)dst*4);
  float4 ex;
  ex.x = __expf(fminf(leaky(a.x + d.x), 80.f));
  ex.y = __expf(fminf(leaky(a.y + d.y), 80.f));
  ex.z = __expf(fminf(leaky(a.z + d.z), 80.f));
  ex.w = __expf(fminf(leaky(a.w + d.w), 80.f));
  *(float4*)(exbuf + (size_t)slot*4) = ex;
}

// ---------------- aggregation L1: pure gather+fma, denom inline, + bias + ELU ----------
__global__ __launch_bounds__(256) void k_agg1(const unsigned short* __restrict__ h1b,
    const float* __restrict__ exbuf,
    const int* __restrict__ rowstart, const int* __restrict__ csr,
    const float* __restrict__ b1, unsigned short* __restrict__ hactb, int n){
  int lane = threadIdx.x & 63;
  int node = blockIdx.x*4 + (threadIdx.x >> 6);
  if (node >= n) return;
  int lo = __builtin_amdgcn_readfirstlane(rowstart[node]);
  int hi = __builtin_amdgcn_readfirstlane(rowstart[node+1]);
  int h = lane >> 4;
  const float* exb = exbuf + h;          // lane reads exbuf[e*4+h]
  float ax=0.f, ay=0.f, az=0.f, aw=0.f, psum=0.f;
  int e = lo;
  for (; e + 7 < hi; e += 8){
    int s0 = csr[e],   s1 = csr[e+1], s2 = csr[e+2], s3 = csr[e+3];   // scalar
    int s4 = csr[e+4], s5 = csr[e+5], s6 = csr[e+6], s7 = csr[e+7];
    float e0 = exb[(size_t)e*4],     e1 = exb[(size_t)(e+1)*4],
          e2 = exb[(size_t)(e+2)*4], e3 = exb[(size_t)(e+3)*4],
          e4 = exb[(size_t)(e+4)*4], e5 = exb[(size_t)(e+5)*4],
          e6 = exb[(size_t)(e+6)*4], e7 = exb[(size_t)(e+7)*4];
    ushort4 u0 = *(const ushort4*)(h1b + (size_t)s0*256 + lane*4);
    ushort4 u1 = *(const ushort4*)(h1b + (size_t)s1*256 + lane*4);
    ushort4 u2 = *(const ushort4*)(h1b + (size_t)s2*256 + lane*4);
    ushort4 u3 = *(const ushort4*)(h1b + (size_t)s3*256 + lane*4);
    ushort4 u4 = *(const ushort4*)(h1b + (size_t)s4*256 + lane*4);
    ushort4 u5 = *(const ushort4*)(h1b + (size_t)s5*256 + lane*4);
    ushort4 u6 = *(const ushort4*)(h1b + (size_t)s6*256 + lane*4);
    ushort4 u7 = *(const ushort4*)(h1b + (size_t)s7*256 + lane*4);
    ax += e0*bf2f(u0.x) + e1*bf2f(u1.x) + e2*bf2f(u2.x) + e3*bf2f(u3.x)
        + e4*bf2f(u4.x) + e5*bf2f(u5.x) + e6*bf2f(u6.x) + e7*bf2f(u7.x);
    ay += e0*bf2f(u0.y) + e1*bf2f(u1.y) + e2*bf2f(u2.y) + e3*bf2f(u3.y)
        + e4*bf2f(u4.y) + e5*bf2f(u5.y) + e6*bf2f(u6.y) + e7*bf2f(u7.y);
    az += e0*bf2f(u0.z) + e1*bf2f(u1.z) + e2*bf2f(u2.z) + e3*bf2f(u3.z)
        + e4*bf2f(u4.z) + e5*bf2f(u5.z) + e6*bf2f(u6.z) + e7*bf2f(u7.z);
    aw += e0*bf2f(u0.w) + e1*bf2f(u1.w) + e2*bf2f(u2.w) + e3*bf2f(u3.w)
        + e4*bf2f(u4.w) + e5*bf2f(u5.w) + e6*bf2f(u6.w) + e7*bf2f(u7.w);
    psum += (e0+e1+e2+e3) + (e4+e5+e6+e7);
  }
  for (; e < hi; ++e){
    int s0 = csr[e];
    float e0 = exb[(size_t)e*4];
    ushort4 u0 = *(const ushort4*)(h1b + (size_t)s0*256 + lane*4);
    ax += e0*bf2f(u0.x); ay += e0*bf2f(u0.y); az += e0*bf2f(u0.z); aw += e0*bf2f(u0.w);
    psum += e0;
  }
  float inv = 1.f/(psum + 1e-16f);
  float4 bv = *(const float4*)(b1 + lane*4);
  float o0 = ax*inv + bv.x, o1 = ay*inv + bv.y, o2 = az*inv + bv.z, o3 = aw*inv + bv.w;
  ushort4 r;
  r.x = f2bf(o0 > 0.f ? o0 : expm1f(o0));
  r.y = f2bf(o1 > 0.f ? o1 : expm1f(o1));
  r.z = f2bf(o2 > 0.f ? o2 : expm1f(o2));
  r.w = f2bf(o3 > 0.f ? o3 : expm1f(o3));
  *(ushort4*)(hactb + (size_t)node*256 + lane*4) = r;
}

// ---------------- GEMM2: hact[M,256]bf16 @ W2[256,40]f32 -> h2b[M,40]bf16 ------------
// + fused att2: as2/ad2 [N] via LDS reduce.
__global__ __launch_bounds__(256) void k_gemm2(const unsigned short* __restrict__ A,
    const float* __restrict__ B, const float* __restrict__ sw, const float* __restrict__ dw,
    unsigned short* __restrict__ Cb, float* __restrict__ as2, float* __restrict__ ad2, int M){
  __shared__ float Xl[32][129];       // pad -> conflict-free column reads
  __shared__ float Wl[128*40];
  __shared__ float Sps[32][8], Spd[32][8];
  int t = threadIdx.x;
  int row0 = blockIdx.x*32;
  int r = t & 31, g = t >> 5;         // g in 0..7 -> cols g*5 .. g*5+4
  float acc[5] = {0,0,0,0,0};
  for (int kt=0; kt<256; kt+=128){
    for (int i=t; i<1280; i+=256)
      *(float4*)&Wl[i*4] = *(const float4*)(B + kt*40 + i*4);
    for (int i=t; i<512; i+=256){     // 32 rows x 128 k, 8 bf16 per chunk
      int rr = i >> 4, k8 = i & 15;
      int grow = row0 + rr; if (grow >= M) grow = M-1;
      uint4 v = *(const uint4*)(A + (size_t)grow*256 + kt + k8*8);
      float* xp = &Xl[rr][k8*8];
      xp[0] = __uint_as_float(v.x << 16); xp[1] = __uint_as_float(v.x & 0xffff0000u);
      xp[2] = __uint_as_float(v.y << 16); xp[3] = __uint_as_float(v.y & 0xffff0000u);
      xp[4] = __uint_as_float(v.z << 16); xp[5] = __uint_as_float(v.z & 0xffff0000u);
      xp[6] = __uint_as_float(v.w << 16); xp[7] = __uint_as_float(v.w & 0xffff0000u);
    }
    __syncthreads();
    #pragma unroll 4
    for (int k=0;k<128;++k){
      float a = Xl[r][k];
      const float* wp = &Wl[k*40 + g*5];
      #pragma unroll
      for (int j=0;j<5;++j) acc[j] += a * wp[j];
    }
    __syncthreads();
  }
  int grow = row0 + r;
  float ps = 0.f, pd = 0.f;
  #pragma unroll
  for (int j=0;j<5;++j){
    ps += acc[j] * sw[g*5+j];
    pd += acc[j] * dw[g*5+j];
  }
  Sps[r][g] = ps; Spd[r][g] = pd;
  if (grow < M){
    #pragma unroll
    for (int j=0;j<5;++j) Cb[(size_t)grow*40 + g*5 + j] = f2bf(acc[j]);
  }
  __syncthreads();
  if (t < 32){
    float a = 0.f, b = 0.f;
    #pragma unroll
    for (int g2=0; g2<8; ++g2){ a += Sps[t][g2]; b += Spd[t][g2]; }
    int rw = row0 + t;
    if (rw < M){ as2[rw] = a; ad2[rw] = b; }
  }
}

// ---------------- pre-pass L2: per-edge ex (no max, single pass) ----------------
__global__ __launch_bounds__(256) void k_pre2(const float* __restrict__ as2,
    const float* __restrict__ ad2, const int* __restrict__ rowstart,
    const int* __restrict__ csr, float* __restrict__ ex2, int n){
  int lane = threadIdx.x & 63;
  int node = blockIdx.x*4 + (threadIdx.x >> 6);
  if (node >= n) return;
  int lo = rowstart[node], hi = rowstart[node+1];
  float adn = ad2[node];
  for (int e = lo + lane; e < hi; e += 64)
    ex2[e] = __expf(fminf(leaky(as2[csr[e]] + adn), 80.f));
}

// ---------------- aggregation L2: gather+fma, denom inline, + bias + log_softmax ------
__global__ __launch_bounds__(256) void k_agg2(const unsigned short* __restrict__ h2b,
    const float* __restrict__ ex2,
    const int* __restrict__ rowstart, const int* __restrict__ csr,
    const float* __restrict__ b2, float* __restrict__ out, int n){
  int lane = threadIdx.x & 63;
  int node = blockIdx.x*4 + (threadIdx.x >> 6);
  if (node >= n) return;
  int lo = __builtin_amdgcn_readfirstlane(rowstart[node]);
  int hi = __builtin_amdgcn_readfirstlane(rowstart[node+1]);
  bool act = lane < 40;
  float acc = 0.f, psum = 0.f;
  int e = lo;
  for (; e + 7 < hi; e += 8){
    int s0 = csr[e],   s1 = csr[e+1], s2 = csr[e+2], s3 = csr[e+3];   // scalar
    int s4 = csr[e+4], s5 = csr[e+5], s6 = csr[e+6], s7 = csr[e+7];
    float e0 = ex2[e],   e1 = ex2[e+1], e2 = ex2[e+2], e3 = ex2[e+3]; // scalar
    float e4 = ex2[e+4], e5 = ex2[e+5], e6 = ex2[e+6], e7 = ex2[e+7];
    float h0 = act ? bf2f(h2b[(size_t)s0*40 + lane]) : 0.f;
    float h1 = act ? bf2f(h2b[(size_t)s1*40 + lane]) : 0.f;
    float h2 = act ? bf2f(h2b[(size_t)s2*40 + lane]) : 0.f;
    float h3 = act ? bf2f(h2b[(size_t)s3*40 + lane]) : 0.f;
    float h4 = act ? bf2f(h2b[(size_t)s4*40 + lane]) : 0.f;
    float h5 = act ? bf2f(h2b[(size_t)s5*40 + lane]) : 0.f;
    float h6 = act ? bf2f(h2b[(size_t)s6*40 + lane]) : 0.f;
    float h7 = act ? bf2f(h2b[(size_t)s7*40 + lane]) : 0.f;
    acc += e0*h0 + e1*h1 + e2*h2 + e3*h3 + e4*h4 + e5*h5 + e6*h6 + e7*h7;
    psum += (e0+e1+e2+e3) + (e4+e5+e6+e7);
  }
  for (; e < hi; ++e){
    int s0 = csr[e]; float e0 = ex2[e];
    acc += e0 * (act ? bf2f(h2b[(size_t)s0*40 + lane]) : 0.f);
    psum += e0;
  }
  float ov = acc/(psum + 1e-16f) + (act ? b2[lane] : 0.f);
  float v = act ? ov : -INFINITY;
  float mx = v;
  #pragma unroll
  for (int o=1;o<64;o<<=1) mx = fmaxf(mx, __shfl_xor(mx,o));
  float ev = act ? __expf(ov - mx) : 0.f;
  float se = ev;
  #pragma unroll
  for (int o=1;o<64;o<<=1) se += __shfl_xor(se,o);
  if (act) out[(size_t)node*40 + lane] = (ov - mx) - __logf(se);
}

extern "C" void kernel_launch(void* const* d_in, const int* in_sizes, int n_in,
                              void* d_out, int out_size, void* d_ws, size_t ws_size,
                              hipStream_t stream){
  const float* x   = (const float*)d_in[0];
  const int*   ei  = (const int*)d_in[1];     // [2,E] int32 (harness contract)
  const float* W1  = (const float*)d_in[2];
  const float* s1w = (const float*)d_in[3];
  const float* d1w = (const float*)d_in[4];
  const float* b1  = (const float*)d_in[5];
  const float* W2  = (const float*)d_in[6];
  const float* s2w = (const float*)d_in[7];
  const float* d2w = (const float*)d_in[8];
  const float* b2  = (const float*)d_in[9];
  float* out = (float*)d_out;

  const int N  = in_sizes[0] / 512;
  const int E  = in_sizes[1] / 2;
  const int Et = E + N;

  // workspace carve-out (~80 MB)
  float* f = (float*)d_ws;
  unsigned short* h1b   = (unsigned short*)f;  f += (size_t)N*128;   // [N][256] bf16
  unsigned short* hactb = (unsigned short*)f;  f += (size_t)N*128;   // [N][256] bf16
  float* as1  = f;  f += (size_t)N*4;
  float* ad1  = f;  f += (size_t)N*4;
  float* as2  = f;  f += N;
  float* ad2  = f;  f += N;
  unsigned short* w1t = (unsigned short*)f;  f += 256*512/2;         // [256][512] bf16
  unsigned short* h2b = (unsigned short*)f;  f += (size_t)N*40/2 + 64; // [N][40] bf16
  float* exbuf = f;  f += (size_t)Et*4;                              // [Et][4] f32
  float* ex2   = f;  f += Et;                                        // [Et] f32
  int* ip = (int*)f;
  int* rowstart = ip;  ip += (N + 4) & ~3;
  int* deg      = ip;  ip += N;
  int* cur      = ip;  ip += N;
  int* csr      = ip;  ip += Et;
  int* bsum     = ip;  ip += 256;

  int nb4 = (N + 3) / 4;
  int nbs = (N + 255) / 256;                 // scan blocks (196 <= 256)
  k_cvt_w<<<512, 256, 0, stream>>>(W1, w1t, deg, N);
  k_count<<<(Et+255)/256, 256, 0, stream>>>(ei, E, N, deg);
  k_scan_a<<<nbs, 256, 0, stream>>>(deg, rowstart, bsum, N);
  k_scan_b<<<1, 256, 0, stream>>>(bsum, nbs);
  k_scan_c<<<nbs, 256, 0, stream>>>(rowstart, bsum, cur, N);
  k_gemm1_mfma<<<dim3((N+63)/64, 2), 256, 0, stream>>>(x, w1t, s1w, d1w, h1b, as1, ad1, N);
  k_fill <<<(Et+255)/256, 256, 0, stream>>>(ei, E, N, rowstart, cur, csr, as1, ad1, exbuf);
  k_agg1 <<<nb4, 256, 0, stream>>>(h1b, exbuf, rowstart, csr, b1, hactb, N);
  k_gemm2<<<(N+31)/32, 256, 0, stream>>>(hactb, W2, s2w, d2w, h2b, as2, ad2, N);
  k_pre2 <<<nb4, 256, 0, stream>>>(as2, ad2, rowstart, csr, ex2, N);
  k_agg2 <<<nb4, 256, 0, stream>>>(h2b, ex2, rowstart, csr, b2, out, N);
}

// Round 4
// 456.900 us; speedup vs baseline: 1.0421x; 1.0421x over previous
//
#include <hip/hip_runtime.h>
#include <math.h>
#include <stdint.h>

// GAT 2-layer: N=50000 nodes, E=800000 edges (+N self loops)
// L1: 512 -> 4 heads x 64 (bf16 MFMA GEMM reading fp32 x directly, cvt fused
//     into A-staging; att1 fused in epilogue), ELU.
// L2: 256 -> 1 head x 40 (att2 fused in gemm2), log_softmax.
//
// R4: gemm1 staging made LINE-CONTIGUOUS (the R0-R3 plateau was the L1
// transaction path: lane-per-row staging = 64 cache lines per instruction).
//  - A: lane->(row,kq) remap: wave covers 16 rows x full 128B line -> 16 lines/instr
//  - B: w1t rebuilt in [kt][kq][col][8k] chunk order so global_load_lds reads
//    1KB contiguous per wave (8 lines/instr) and lands linearly in the
//    [kq][col] LDS layout the MFMA fragment reads expect (read side unchanged).
//  - 6 blocks/CU (LDS 24KB, launch_bounds(256,6)).

typedef short bf16x8 __attribute__((ext_vector_type(8)));
typedef float f32x4  __attribute__((ext_vector_type(4)));

static __device__ __forceinline__ float leaky(float x){ return x > 0.f ? x : 0.2f*x; }
static __device__ __forceinline__ unsigned short f2bf(float f){
  uint32_t u = __float_as_uint(f);
  uint32_t r = u + 0x7fffu + ((u >> 16) & 1u);   // RNE
  return (unsigned short)(r >> 16);
}
static __device__ __forceinline__ float bf2f(unsigned short u){
  return __uint_as_float(((uint32_t)u) << 16);
}

// ------- convert W1 -> w1t2 bf16 in [kt][kq][col][8] chunk order; zero deg -------
// chunk(kt,kq,col) holds W1[k= kt*32+kq*8 .. +8][col] (8 consecutive k, one col).
__global__ void k_cvt_w(const float* __restrict__ W, unsigned short* __restrict__ wt,
                        int* __restrict__ deg, int n){
  int i = blockIdx.x*blockDim.x + threadIdx.x;
  if (i < n) deg[i] = 0;
  if (i >= 256*64) return;
  int col = i & 255, kg = i >> 8;        // kg in [0,64): k = kg*8 .. +8
  int kt = kg >> 2, kq = kg & 3;
  unsigned short* dst = wt + ((size_t)kt*1024 + kq*256 + col)*8;
  bf16x8 p;
  #pragma unroll
  for (int j=0;j<8;j++) p[j] = (short)f2bf(W[(size_t)(kg*8+j)*256 + col]);
  *(bf16x8*)dst = p;
}

// ---------------- count in-degree (incl self loops) ----------------
__global__ void k_count(const int* __restrict__ ei, int E, int n, int* __restrict__ deg){
  int i = blockIdx.x*blockDim.x + threadIdx.x;
  int tot = E + n;
  if (i >= tot) return;
  int dst = (i < E) ? ei[E + i] : (i - E);
  atomicAdd(&deg[dst], 1);
}

// ---------------- multi-block exclusive scan: deg[n] -> rowstart[0..n] ----------------
__global__ __launch_bounds__(256) void k_scan_a(const int* __restrict__ deg,
    int* __restrict__ rowstart, int* __restrict__ bsum, int n){
  __shared__ int sm[256];
  int b = blockIdx.x, t = threadIdx.x;
  int i = b*256 + t;
  int v = (i < n) ? deg[i] : 0;
  sm[t] = v;
  __syncthreads();
  for (int off=1; off<256; off<<=1){
    int u = (t >= off) ? sm[t-off] : 0;
    __syncthreads();
    sm[t] += u;
    __syncthreads();
  }
  if (i < n) rowstart[i+1] = sm[t];
  if (t == 255) bsum[b] = sm[255];
}
__global__ __launch_bounds__(256) void k_scan_b(int* __restrict__ bsum, int nb){
  __shared__ int sm[256];
  int t = threadIdx.x;
  int v = (t < nb) ? bsum[t] : 0;
  sm[t] = v;
  __syncthreads();
  for (int off=1; off<256; off<<=1){
    int u = (t >= off) ? sm[t-off] : 0;
    __syncthreads();
    sm[t] += u;
    __syncthreads();
  }
  if (t < nb) bsum[t] = sm[t] - v;   // exclusive prefix
}
__global__ __launch_bounds__(256) void k_scan_c(int* __restrict__ rowstart,
    const int* __restrict__ bsum, int* __restrict__ cur, int n){
  int b = blockIdx.x, t = threadIdx.x;
  int i = b*256 + t;
  if (i < n){ rowstart[i+1] += bsum[b]; cur[i] = 0; }
  if (i == 0) rowstart[0] = 0;
}

// ---------------- GEMM1 (bf16 MFMA, fp32 A with fused cvt) + fused att1 ----------
// Tile 64 rows x 128 cols, 4 waves. Staging per 32-k step:
//   A: lane l of wave w -> row w*16+(l&15), kq=l>>4; reads 32B contiguous;
//      wave covers 16 rows x 128B full lines (16 lines/instr).
//   B: thread t -> chunks t, t+256 of [kq][col] layout; w1t2 is pre-ordered so
//      consecutive threads read consecutive 16B chunks (1KB/wave, 8 lines/instr)
//      via global_load_lds (linear LDS dest == [kq][col] layout).
__global__ __launch_bounds__(256, 6) void k_gemm1_mfma(const float* __restrict__ X,
                                                    const unsigned short* __restrict__ WT,
                                                    const float* __restrict__ SW,
                                                    const float* __restrict__ DW,
                                                    unsigned short* __restrict__ Cb,
                                                    float* __restrict__ as1,
                                                    float* __restrict__ ad1, int M){
  __shared__ __align__(16) unsigned short lA[2][2048];  // 2 x 4 KB : [kq][row] chunks
  __shared__ __align__(16) unsigned short lB[2][4096];  // 2 x 8 KB : [kq][col] chunks
  const int t = threadIdx.x;
  const int lane = t & 63, w = t >> 6;
  const int wx = w & 1, wy = w >> 1;
  const int row0 = blockIdx.x * 64, col0 = blockIdx.y * 128;

  f32x4 acc[2][4];
  #pragma unroll
  for (int i=0;i<2;i++)
    #pragma unroll
    for (int j=0;j<4;j++)
      #pragma unroll
      for (int r=0;r<4;r++) acc[i][j][r] = 0.f;

  // A staging: row = w*16 + (lane&15), kA = lane>>4  (32B span per thread)
  const int rA = w*16 + (lane & 15);
  const int kA = lane >> 4;
  const float* xA = X + (size_t)min(row0 + rA, M-1)*512 + kA*8;
  const int aChunk = kA*64 + rA;                 // LDS chunk idx [kq][row]

  // B staging: chunks c0 = t, c1 = t+256 of [kq][col]; global chunk idx =
  // KT*1024 + (c>>7)*256 + col0 + (c&127)
  const int c0 = t, c1 = t + 256;
  const unsigned short* bB0 = WT + ((size_t)(c0>>7)*256 + col0 + (c0&127))*8;
  const unsigned short* bB1 = WT + ((size_t)(c1>>7)*256 + col0 + (c1&127))*8;

  const int fkq = lane >> 4, li = lane & 15;     // MFMA fragment coords

#define ISSUE_B(NXT, KT) do{ \
  __builtin_amdgcn_global_load_lds((const __attribute__((address_space(1))) void*)(bB0 + (size_t)(KT)*8192), \
      (__attribute__((address_space(3))) void*)&lB[NXT][c0*8], 16, 0, 0); \
  __builtin_amdgcn_global_load_lds((const __attribute__((address_space(1))) void*)(bB1 + (size_t)(KT)*8192), \
      (__attribute__((address_space(3))) void*)&lB[NXT][c1*8], 16, 0, 0); }while(0)

#define CVT_WRITE(NXT, S0,S1) do{ \
  bf16x8 p0; \
  p0[0]=(short)f2bf(S0.x); p0[1]=(short)f2bf(S0.y); p0[2]=(short)f2bf(S0.z); p0[3]=(short)f2bf(S0.w); \
  p0[4]=(short)f2bf(S1.x); p0[5]=(short)f2bf(S1.y); p0[6]=(short)f2bf(S1.z); p0[7]=(short)f2bf(S1.w); \
  *(bf16x8*)&lA[NXT][aChunk*8] = p0; }while(0)

#define STEP(T, CUR) do{ \
  float4 n0, n1; \
  if ((T) < 15){ \
    n0 = *(const float4*)(xA + ((T)+1)*32); \
    n1 = *(const float4*)(xA + ((T)+1)*32 + 4); \
    ISSUE_B((CUR)^1, (T)+1); \
  } \
  bf16x8 af[2], bfr[4]; \
  _Pragma("unroll") \
  for (int i=0;i<2;i++) \
    af[i]  = *(const bf16x8*)&lA[CUR][(fkq*64 + wx*32 + i*16 + li)*8]; \
  _Pragma("unroll") \
  for (int j=0;j<4;j++) \
    bfr[j] = *(const bf16x8*)&lB[CUR][(fkq*128 + wy*64 + j*16 + li)*8]; \
  _Pragma("unroll") \
  for (int i=0;i<2;i++) \
    _Pragma("unroll") \
    for (int j=0;j<4;j++) \
      acc[i][j] = __builtin_amdgcn_mfma_f32_16x16x32_bf16(af[i], bfr[j], acc[i][j], 0, 0, 0); \
  if ((T) < 15){ \
    CVT_WRITE((CUR)^1, n0, n1); \
    __syncthreads(); \
  } \
}while(0)

  // ---- prologue: stage tile 0 into buf 0
  {
    float4 a0 = *(const float4*)(xA);
    float4 a1 = *(const float4*)(xA + 4);
    ISSUE_B(0, 0);
    CVT_WRITE(0, a0, a1);
    __syncthreads();
  }

  // ---- 16 K-steps, fully unrolled, buffers ping-pong at compile time
  #pragma unroll
  for (int tt = 0; tt < 8; ++tt){
    STEP(2*tt,   (0));
    STEP(2*tt+1, (1));
  }

#undef STEP
#undef CVT_WRITE
#undef ISSUE_B

  // epilogue 1: C store. C/D map col=lane&15, row=(lane>>4)*4+reg
  #pragma unroll
  for (int i=0;i<2;i++){
    #pragma unroll
    for (int r=0;r<4;r++){
      int row = row0 + wx*32 + i*16 + fkq*4 + r;
      if (row < M){
        #pragma unroll
        for (int j=0;j<4;j++)
          Cb[(size_t)row*256 + col0 + wy*64 + j*16 + li] = f2bf(acc[i][j][r]);
      }
    }
  }

  // epilogue 2: fused att1 dots for head hw (this wave's 64-col span)
  const int hw = (int)blockIdx.y*2 + wy;
  float sv[4], dv[4];
  #pragma unroll
  for (int j=0;j<4;j++){
    sv[j] = SW[hw*64 + j*16 + li];
    dv[j] = DW[hw*64 + j*16 + li];
  }
  #pragma unroll
  for (int i=0;i<2;i++){
    #pragma unroll
    for (int r=0;r<4;r++){
      float ps = acc[i][0][r]*sv[0] + acc[i][1][r]*sv[1] + acc[i][2][r]*sv[2] + acc[i][3][r]*sv[3];
      float pd = acc[i][0][r]*dv[0] + acc[i][1][r]*dv[1] + acc[i][2][r]*dv[2] + acc[i][3][r]*dv[3];
      #pragma unroll
      for (int o=1;o<16;o<<=1){ ps += __shfl_xor(ps,o); pd += __shfl_xor(pd,o); }
      int row = row0 + wx*32 + i*16 + fkq*4 + r;
      if (li == 0 && row < M){
        as1[row*4 + hw] = ps;
        ad1[row*4 + hw] = pd;
      }
    }
  }
}

// ---------------- scatter edges into CSR + compute per-edge ex (4 heads) ----------
__global__ void k_fill(const int* __restrict__ ei, int E, int n,
                       const int* __restrict__ rowstart, int* __restrict__ cur,
                       int* __restrict__ csr,
                       const float* __restrict__ as1, const float* __restrict__ ad1,
                       float* __restrict__ exbuf){
  int i = blockIdx.x*blockDim.x + threadIdx.x;
  int tot = E + n;
  if (i >= tot) return;
  int src, dst;
  if (i < E){ src = ei[i]; dst = ei[E+i]; } else { src = i - E; dst = src; }
  int pos = atomicAdd(&cur[dst], 1);
  int slot = rowstart[dst] + pos;
  csr[slot] = src;
  float4 a = *(const float4*)(as1 + (size_t)src*4);
  float4 d = *(const float4*)(ad1 + (size_t)dst*4);
  float4 ex;
  ex.x = __expf(fminf(leaky(a.x + d.x), 80.f));
  ex.y = __expf(fminf(leaky(a.y + d.y), 80.f));
  ex.z = __expf(fminf(leaky(a.z + d.z), 80.f));
  ex.w = __expf(fminf(leaky(a.w + d.w), 80.f));
  *(float4*)(exbuf + (size_t)slot*4) = ex;
}

// ---------------- aggregation L1: pure gather+fma, denom inline, + bias + ELU ----------
__global__ __launch_bounds__(256) void k_agg1(const unsigned short* __restrict__ h1b,
    const float* __restrict__ exbuf,
    const int* __restrict__ rowstart, const int* __restrict__ csr,
    const float* __restrict__ b1, unsigned short* __restrict__ hactb, int n){
  int lane = threadIdx.x & 63;
  int node = blockIdx.x*4 + (threadIdx.x >> 6);
  if (node >= n) return;
  int lo = __builtin_amdgcn_readfirstlane(rowstart[node]);
  int hi = __builtin_amdgcn_readfirstlane(rowstart[node+1]);
  int h = lane >> 4;
  const float* exb = exbuf + h;          // lane reads exbuf[e*4+h]
  float ax=0.f, ay=0.f, az=0.f, aw=0.f, psum=0.f;
  int e = lo;
  for (; e + 7 < hi; e += 8){
    int s0 = csr[e],   s1 = csr[e+1], s2 = csr[e+2], s3 = csr[e+3];   // scalar
    int s4 = csr[e+4], s5 = csr[e+5], s6 = csr[e+6], s7 = csr[e+7];
    float e0 = exb[(size_t)e*4],     e1 = exb[(size_t)(e+1)*4],
          e2 = exb[(size_t)(e+2)*4], e3 = exb[(size_t)(e+3)*4],
          e4 = exb[(size_t)(e+4)*4], e5 = exb[(size_t)(e+5)*4],
          e6 = exb[(size_t)(e+6)*4], e7 = exb[(size_t)(e+7)*4];
    ushort4 u0 = *(const ushort4*)(h1b + (size_t)s0*256 + lane*4);
    ushort4 u1 = *(const ushort4*)(h1b + (size_t)s1*256 + lane*4);
    ushort4 u2 = *(const ushort4*)(h1b + (size_t)s2*256 + lane*4);
    ushort4 u3 = *(const ushort4*)(h1b + (size_t)s3*256 + lane*4);
    ushort4 u4 = *(const ushort4*)(h1b + (size_t)s4*256 + lane*4);
    ushort4 u5 = *(const ushort4*)(h1b + (size_t)s5*256 + lane*4);
    ushort4 u6 = *(const ushort4*)(h1b + (size_t)s6*256 + lane*4);
    ushort4 u7 = *(const ushort4*)(h1b + (size_t)s7*256 + lane*4);
    ax += e0*bf2f(u0.x) + e1*bf2f(u1.x) + e2*bf2f(u2.x) + e3*bf2f(u3.x)
        + e4*bf2f(u4.x) + e5*bf2f(u5.x) + e6*bf2f(u6.x) + e7*bf2f(u7.x);
    ay += e0*bf2f(u0.y) + e1*bf2f(u1.y) + e2*bf2f(u2.y) + e3*bf2f(u3.y)
        + e4*bf2f(u4.y) + e5*bf2f(u5.y) + e6*bf2f(u6.y) + e7*bf2f(u7.y);
    az += e0*bf2f(u0.z) + e1*bf2f(u1.z) + e2*bf2f(u2.z) + e3*bf2f(u3.z)
        + e4*bf2f(u4.z) + e5*bf2f(u5.z) + e6*bf2f(u6.z) + e7*bf2f(u7.z);
    aw += e0*bf2f(u0.w) + e1*bf2f(u1.w) + e2*bf2f(u2.w) + e3*bf2f(u3.w)
        + e4*bf2f(u4.w) + e5*bf2f(u5.w) + e6*bf2f(u6.w) + e7*bf2f(u7.w);
    psum += (e0+e1+e2+e3) + (e4+e5+e6+e7);
  }
  for (; e < hi; ++e){
    int s0 = csr[e];
    float e0 = exb[(size_t)e*4];
    ushort4 u0 = *(const ushort4*)(h1b + (size_t)s0*256 + lane*4);
    ax += e0*bf2f(u0.x); ay += e0*bf2f(u0.y); az += e0*bf2f(u0.z); aw += e0*bf2f(u0.w);
    psum += e0;
  }
  float inv = 1.f/(psum + 1e-16f);
  float4 bv = *(const float4*)(b1 + lane*4);
  float o0 = ax*inv + bv.x, o1 = ay*inv + bv.y, o2 = az*inv + bv.z, o3 = aw*inv + bv.w;
  ushort4 r;
  r.x = f2bf(o0 > 0.f ? o0 : expm1f(o0));
  r.y = f2bf(o1 > 0.f ? o1 : expm1f(o1));
  r.z = f2bf(o2 > 0.f ? o2 : expm1f(o2));
  r.w = f2bf(o3 > 0.f ? o3 : expm1f(o3));
  *(ushort4*)(hactb + (size_t)node*256 + lane*4) = r;
}

// ---------------- GEMM2: hact[M,256]bf16 @ W2[256,40]f32 -> h2b[M,40]bf16 ------------
// + fused att2: as2/ad2 [N] via LDS reduce.
__global__ __launch_bounds__(256) void k_gemm2(const unsigned short* __restrict__ A,
    const float* __restrict__ B, const float* __restrict__ sw, const float* __restrict__ dw,
    unsigned short* __restrict__ Cb, float* __restrict__ as2, float* __restrict__ ad2, int M){
  __shared__ float Xl[32][129];       // pad -> conflict-free column reads
  __shared__ float Wl[128*40];
  __shared__ float Sps[32][8], Spd[32][8];
  int t = threadIdx.x;
  int row0 = blockIdx.x*32;
  int r = t & 31, g = t >> 5;         // g in 0..7 -> cols g*5 .. g*5+4
  float acc[5] = {0,0,0,0,0};
  for (int kt=0; kt<256; kt+=128){
    for (int i=t; i<1280; i+=256)
      *(float4*)&Wl[i*4] = *(const float4*)(B + kt*40 + i*4);
    for (int i=t; i<512; i+=256){     // 32 rows x 128 k, 8 bf16 per chunk
      int rr = i >> 4, k8 = i & 15;
      int grow = row0 + rr; if (grow >= M) grow = M-1;
      uint4 v = *(const uint4*)(A + (size_t)grow*256 + kt + k8*8);
      float* xp = &Xl[rr][k8*8];
      xp[0] = __uint_as_float(v.x << 16); xp[1] = __uint_as_float(v.x & 0xffff0000u);
      xp[2] = __uint_as_float(v.y << 16); xp[3] = __uint_as_float(v.y & 0xffff0000u);
      xp[4] = __uint_as_float(v.z << 16); xp[5] = __uint_as_float(v.z & 0xffff0000u);
      xp[6] = __uint_as_float(v.w << 16); xp[7] = __uint_as_float(v.w & 0xffff0000u);
    }
    __syncthreads();
    #pragma unroll 4
    for (int k=0;k<128;++k){
      float a = Xl[r][k];
      const float* wp = &Wl[k*40 + g*5];
      #pragma unroll
      for (int j=0;j<5;++j) acc[j] += a * wp[j];
    }
    __syncthreads();
  }
  int grow = row0 + r;
  float ps = 0.f, pd = 0.f;
  #pragma unroll
  for (int j=0;j<5;++j){
    ps += acc[j] * sw[g*5+j];
    pd += acc[j] * dw[g*5+j];
  }
  Sps[r][g] = ps; Spd[r][g] = pd;
  if (grow < M){
    #pragma unroll
    for (int j=0;j<5;++j) Cb[(size_t)grow*40 + g*5 + j] = f2bf(acc[j]);
  }
  __syncthreads();
  if (t < 32){
    float a = 0.f, b = 0.f;
    #pragma unroll
    for (int g2=0; g2<8; ++g2){ a += Sps[t][g2]; b += Spd[t][g2]; }
    int rw = row0 + t;
    if (rw < M){ as2[rw] = a; ad2[rw] = b; }
  }
}

// ---------------- pre-pass L2: per-edge ex (no max, single pass) ----------------
__global__ __launch_bounds__(256) void k_pre2(const float* __restrict__ as2,
    const float* __restrict__ ad2, const int* __restrict__ rowstart,
    const int* __restrict__ csr, float* __restrict__ ex2, int n){
  int lane = threadIdx.x & 63;
  int node = blockIdx.x*4 + (threadIdx.x >> 6);
  if (node >= n) return;
  int lo = rowstart[node], hi = rowstart[node+1];
  float adn = ad2[node];
  for (int e = lo + lane; e < hi; e += 64)
    ex2[e] = __expf(fminf(leaky(as2[csr[e]] + adn), 80.f));
}

// ---------------- aggregation L2: gather+fma, denom inline, + bias + log_softmax ------
__global__ __launch_bounds__(256) void k_agg2(const unsigned short* __restrict__ h2b,
    const float* __restrict__ ex2,
    const int* __restrict__ rowstart, const int* __restrict__ csr,
    const float* __restrict__ b2, float* __restrict__ out, int n){
  int lane = threadIdx.x & 63;
  int node = blockIdx.x*4 + (threadIdx.x >> 6);
  if (node >= n) return;
  int lo = __builtin_amdgcn_readfirstlane(rowstart[node]);
  int hi = __builtin_amdgcn_readfirstlane(rowstart[node+1]);
  bool act = lane < 40;
  float acc = 0.f, psum = 0.f;
  int e = lo;
  for (; e + 7 < hi; e += 8){
    int s0 = csr[e],   s1 = csr[e+1], s2 = csr[e+2], s3 = csr[e+3];   // scalar
    int s4 = csr[e+4], s5 = csr[e+5], s6 = csr[e+6], s7 = csr[e+7];
    float e0 = ex2[e],   e1 = ex2[e+1], e2 = ex2[e+2], e3 = ex2[e+3]; // scalar
    float e4 = ex2[e+4], e5 = ex2[e+5], e6 = ex2[e+6], e7 = ex2[e+7];
    float h0 = act ? bf2f(h2b[(size_t)s0*40 + lane]) : 0.f;
    float h1 = act ? bf2f(h2b[(size_t)s1*40 + lane]) : 0.f;
    float h2 = act ? bf2f(h2b[(size_t)s2*40 + lane]) : 0.f;
    float h3 = act ? bf2f(h2b[(size_t)s3*40 + lane]) : 0.f;
    float h4 = act ? bf2f(h2b[(size_t)s4*40 + lane]) : 0.f;
    float h5 = act ? bf2f(h2b[(size_t)s5*40 + lane]) : 0.f;
    float h6 = act ? bf2f(h2b[(size_t)s6*40 + lane]) : 0.f;
    float h7 = act ? bf2f(h2b[(size_t)s7*40 + lane]) : 0.f;
    acc += e0*h0 + e1*h1 + e2*h2 + e3*h3 + e4*h4 + e5*h5 + e6*h6 + e7*h7;
    psum += (e0+e1+e2+e3) + (e4+e5+e6+e7);
  }
  for (; e < hi; ++e){
    int s0 = csr[e]; float e0 = ex2[e];
    acc += e0 * (act ? bf2f(h2b[(size_t)s0*40 + lane]) : 0.f);
    psum += e0;
  }
  float ov = acc/(psum + 1e-16f) + (act ? b2[lane] : 0.f);
  float v = act ? ov : -INFINITY;
  float mx = v;
  #pragma unroll
  for (int o=1;o<64;o<<=1) mx = fmaxf(mx, __shfl_xor(mx,o));
  float ev = act ? __expf(ov - mx) : 0.f;
  float se = ev;
  #pragma unroll
  for (int o=1;o<64;o<<=1) se += __shfl_xor(se,o);
  if (act) out[(size_t)node*40 + lane] = (ov - mx) - __logf(se);
}

extern "C" void kernel_launch(void* const* d_in, const int* in_sizes, int n_in,
                              void* d_out, int out_size, void* d_ws, size_t ws_size,
                              hipStream_t stream){
  const float* x   = (const float*)d_in[0];
  const int*   ei  = (const int*)d_in[1];     // [2,E] int32 (harness contract)
  const float* W1  = (const float*)d_in[2];
  const float* s1w = (const float*)d_in[3];
  const float* d1w = (const float*)d_in[4];
  const float* b1  = (const float*)d_in[5];
  const float* W2  = (const float*)d_in[6];
  const float* s2w = (const float*)d_in[7];
  const float* d2w = (const float*)d_in[8];
  const float* b2  = (const float*)d_in[9];
  float* out = (float*)d_out;

  const int N  = in_sizes[0] / 512;
  const int E  = in_sizes[1] / 2;
  const int Et = E + N;

  // workspace carve-out (~80 MB)
  float* f = (float*)d_ws;
  unsigned short* h1b   = (unsigned short*)f;  f += (size_t)N*128;   // [N][256] bf16
  unsigned short* hactb = (unsigned short*)f;  f += (size_t)N*128;   // [N][256] bf16
  float* as1  = f;  f += (size_t)N*4;
  float* ad1  = f;  f += (size_t)N*4;
  float* as2  = f;  f += N;
  float* ad2  = f;  f += N;
  unsigned short* w1t = (unsigned short*)f;  f += 256*512/2;         // [kt][kq][col][8] bf16
  unsigned short* h2b = (unsigned short*)f;  f += (size_t)N*40/2 + 64; // [N][40] bf16
  float* exbuf = f;  f += (size_t)Et*4;                              // [Et][4] f32
  float* ex2   = f;  f += Et;                                        // [Et] f32
  int* ip = (int*)f;
  int* rowstart = ip;  ip += (N + 4) & ~3;
  int* deg      = ip;  ip += N;
  int* cur      = ip;  ip += N;
  int* csr      = ip;  ip += Et;
  int* bsum     = ip;  ip += 256;

  int nb4 = (N + 3) / 4;
  int nbs = (N + 255) / 256;                 // scan blocks (196 <= 256)
  k_cvt_w<<<nbs, 256, 0, stream>>>(W1, w1t, deg, N);
  k_count<<<(Et+255)/256, 256, 0, stream>>>(ei, E, N, deg);
  k_scan_a<<<nbs, 256, 0, stream>>>(deg, rowstart, bsum, N);
  k_scan_b<<<1, 256, 0, stream>>>(bsum, nbs);
  k_scan_c<<<nbs, 256, 0, stream>>>(rowstart, bsum, cur, N);
  k_gemm1_mfma<<<dim3((N+63)/64, 2), 256, 0, stream>>>(x, w1t, s1w, d1w, h1b, as1, ad1, N);
  k_fill <<<(Et+255)/256, 256, 0, stream>>>(ei, E, N, rowstart, cur, csr, as1, ad1, exbuf);
  k_agg1 <<<nb4, 256, 0, stream>>>(h1b, exbuf, rowstart, csr, b1, hactb, N);
  k_gemm2<<<(N+31)/32, 256, 0, stream>>>(hactb, W2, s2w, d2w, h2b, as2, ad2, N);
  k_pre2 <<<nb4, 256, 0, stream>>>(as2, ad2, rowstart, csr, ex2, N);
  k_agg2 <<<nb4, 256, 0, stream>>>(h2b, ex2, rowstart, csr, b2, out, N);
}

// Round 5
// 455.299 us; speedup vs baseline: 1.0457x; 1.0035x over previous
//
#include <hip/hip_runtime.h>
#include <math.h>
#include <stdint.h>

// GAT 2-layer: N=50000 nodes, E=800000 edges (+N self loops)
// L1: 512 -> 4 heads x 64 (bf16 MFMA GEMM reading fp32 x directly, cvt fused
//     into A-staging; att1 fused in epilogue), ELU.
// L2: 256 -> 1 head x 40 (att2 fused in gemm2), log_softmax.
//
// R5: gemm1 pipeline with NO vmcnt on the structural path:
//  - B staging moved from global_load_lds to registers (plain loads; w1t chunk
//    layout keeps 1KB/wave contiguity). All global loads are now private VGPR
//    loads -> a barrier has no correctness claim on them.
//  - raw s_barrier with only lgkmcnt(0) (LDS visibility); NO vmcnt(0) drain.
//  - depth-2 reg rotation (P/Q named sets, static): load tile t+3 at step t,
//    write tile t+1; compiler derives counted vmcnt from dataflow (race-free).

typedef short bf16x8 __attribute__((ext_vector_type(8)));
typedef float f32x4  __attribute__((ext_vector_type(4)));

static __device__ __forceinline__ float leaky(float x){ return x > 0.f ? x : 0.2f*x; }
static __device__ __forceinline__ unsigned short f2bf(float f){
  uint32_t u = __float_as_uint(f);
  uint32_t r = u + 0x7fffu + ((u >> 16) & 1u);   // RNE
  return (unsigned short)(r >> 16);
}
static __device__ __forceinline__ float bf2f(unsigned short u){
  return __uint_as_float(((uint32_t)u) << 16);
}

// ------- convert W1 -> w1t bf16 in [kt][kq][col][8] chunk order; zero deg -------
// chunk(kt,kq,col) holds W1[k= kt*32+kq*8 .. +8][col] (8 consecutive k, one col).
__global__ void k_cvt_w(const float* __restrict__ W, unsigned short* __restrict__ wt,
                        int* __restrict__ deg, int n){
  int i = blockIdx.x*blockDim.x + threadIdx.x;
  if (i < n) deg[i] = 0;
  if (i >= 256*64) return;
  int col = i & 255, kg = i >> 8;        // kg in [0,64): k = kg*8 .. +8
  int kt = kg >> 2, kq = kg & 3;
  unsigned short* dst = wt + ((size_t)kt*1024 + kq*256 + col)*8;
  bf16x8 p;
  #pragma unroll
  for (int j=0;j<8;j++) p[j] = (short)f2bf(W[(size_t)(kg*8+j)*256 + col]);
  *(bf16x8*)dst = p;
}

// ---------------- count in-degree (incl self loops) ----------------
__global__ void k_count(const int* __restrict__ ei, int E, int n, int* __restrict__ deg){
  int i = blockIdx.x*blockDim.x + threadIdx.x;
  int tot = E + n;
  if (i >= tot) return;
  int dst = (i < E) ? ei[E + i] : (i - E);
  atomicAdd(&deg[dst], 1);
}

// ---------------- multi-block exclusive scan: deg[n] -> rowstart[0..n] ----------------
__global__ __launch_bounds__(256) void k_scan_a(const int* __restrict__ deg,
    int* __restrict__ rowstart, int* __restrict__ bsum, int n){
  __shared__ int sm[256];
  int b = blockIdx.x, t = threadIdx.x;
  int i = b*256 + t;
  int v = (i < n) ? deg[i] : 0;
  sm[t] = v;
  __syncthreads();
  for (int off=1; off<256; off<<=1){
    int u = (t >= off) ? sm[t-off] : 0;
    __syncthreads();
    sm[t] += u;
    __syncthreads();
  }
  if (i < n) rowstart[i+1] = sm[t];
  if (t == 255) bsum[b] = sm[255];
}
__global__ __launch_bounds__(256) void k_scan_b(int* __restrict__ bsum, int nb){
  __shared__ int sm[256];
  int t = threadIdx.x;
  int v = (t < nb) ? bsum[t] : 0;
  sm[t] = v;
  __syncthreads();
  for (int off=1; off<256; off<<=1){
    int u = (t >= off) ? sm[t-off] : 0;
    __syncthreads();
    sm[t] += u;
    __syncthreads();
  }
  if (t < nb) bsum[t] = sm[t] - v;   // exclusive prefix
}
__global__ __launch_bounds__(256) void k_scan_c(int* __restrict__ rowstart,
    const int* __restrict__ bsum, int* __restrict__ cur, int n){
  int b = blockIdx.x, t = threadIdx.x;
  int i = b*256 + t;
  if (i < n){ rowstart[i+1] += bsum[b]; cur[i] = 0; }
  if (i == 0) rowstart[0] = 0;
}

// ---------------- GEMM1 (bf16 MFMA, fp32 A with fused cvt) + fused att1 ----------
// Tile 64 rows x 128 cols, 4 waves. All staging via registers:
//   A: lane -> (row w*16+(l&15), kq=l>>4): wave covers 16 rows x full 128B lines.
//   B: thread t -> chunks t, t+256 of [kq][col] (w1t pre-ordered, 1KB/wave).
// Pipeline: step t consumes buf[cur]; writes tile t+1 from reg set; loads tile
// t+3 into that set; barrier = lgkmcnt(0)+s_barrier (no vmcnt drain).
__global__ __launch_bounds__(256, 4) void k_gemm1_mfma(const float* __restrict__ X,
                                                    const unsigned short* __restrict__ WT,
                                                    const float* __restrict__ SW,
                                                    const float* __restrict__ DW,
                                                    unsigned short* __restrict__ Cb,
                                                    float* __restrict__ as1,
                                                    float* __restrict__ ad1, int M){
  __shared__ __align__(16) unsigned short lA[2][2048];  // 2 x 4 KB : [kq][row] chunks
  __shared__ __align__(16) unsigned short lB[2][4096];  // 2 x 8 KB : [kq][col] chunks
  const int t = threadIdx.x;
  const int lane = t & 63, w = t >> 6;
  const int wx = w & 1, wy = w >> 1;
  const int row0 = blockIdx.x * 64, col0 = blockIdx.y * 128;

  f32x4 acc[2][4];
  #pragma unroll
  for (int i=0;i<2;i++)
    #pragma unroll
    for (int j=0;j<4;j++)
      #pragma unroll
      for (int r=0;r<4;r++) acc[i][j][r] = 0.f;

  // A staging: row = w*16 + (lane&15), kA = lane>>4  (32B span per thread)
  const int rA = w*16 + (lane & 15);
  const int kA = lane >> 4;
  const float* xA = X + (size_t)min(row0 + rA, M-1)*512 + kA*8;
  const int aChunk = kA*64 + rA;                 // LDS chunk idx [kq][row]

  // B staging: chunks c0 = t, c1 = t+256 of [kq][col]
  const int c0 = t, c1 = t + 256;
  const unsigned short* bB0 = WT + ((size_t)(c0>>7)*256 + col0 + (c0&127))*8;
  const unsigned short* bB1 = WT + ((size_t)(c1>>7)*256 + col0 + (c1&127))*8;

  const int fkq = lane >> 4, li = lane & 15;     // MFMA fragment coords

  float4 pA0, pA1, qA0, qA1;
  uint4  pB0, pB1, qB0, qB1;

#define LOAD_T(A0,A1,B0,B1, T) do{ \
  A0 = *(const float4*)(xA + (T)*32); \
  A1 = *(const float4*)(xA + (T)*32 + 4); \
  B0 = *(const uint4*)(bB0 + (size_t)(T)*8192); \
  B1 = *(const uint4*)(bB1 + (size_t)(T)*8192); }while(0)

#define WRITE_T(NXT, A0,A1,B0,B1) do{ \
  bf16x8 p0; \
  p0[0]=(short)f2bf(A0.x); p0[1]=(short)f2bf(A0.y); p0[2]=(short)f2bf(A0.z); p0[3]=(short)f2bf(A0.w); \
  p0[4]=(short)f2bf(A1.x); p0[5]=(short)f2bf(A1.y); p0[6]=(short)f2bf(A1.z); p0[7]=(short)f2bf(A1.w); \
  *(bf16x8*)&lA[NXT][aChunk*8] = p0; \
  *(uint4*)&lB[NXT][c0*8] = B0; \
  *(uint4*)&lB[NXT][c1*8] = B1; }while(0)

#define BARRIER() do{ \
  asm volatile("s_waitcnt lgkmcnt(0)" ::: "memory"); \
  __builtin_amdgcn_s_barrier(); \
  asm volatile("" ::: "memory"); }while(0)

#define STEP(T, CUR, A0,A1,B0,B1) do{ \
  bf16x8 af[2], bfr[4]; \
  _Pragma("unroll") \
  for (int i=0;i<2;i++) \
    af[i]  = *(const bf16x8*)&lA[CUR][(fkq*64 + wx*32 + i*16 + li)*8]; \
  _Pragma("unroll") \
  for (int j=0;j<4;j++) \
    bfr[j] = *(const bf16x8*)&lB[CUR][(fkq*128 + wy*64 + j*16 + li)*8]; \
  _Pragma("unroll") \
  for (int i=0;i<2;i++) \
    _Pragma("unroll") \
    for (int j=0;j<4;j++) \
      acc[i][j] = __builtin_amdgcn_mfma_f32_16x16x32_bf16(af[i], bfr[j], acc[i][j], 0, 0, 0); \
  if ((T) < 15){ \
    WRITE_T((CUR)^1, A0,A1,B0,B1); \
    if ((T) <= 12) LOAD_T(A0,A1,B0,B1, (T)+3); \
    BARRIER(); \
  } \
}while(0)

  // ---- prologue: tile0 -> buf0; prefetch tile1 (P), tile2 (Q)
  {
    LOAD_T(pA0,pA1,pB0,pB1, 0);
    WRITE_T(0, pA0,pA1,pB0,pB1);
    LOAD_T(pA0,pA1,pB0,pB1, 1);
    LOAD_T(qA0,qA1,qB0,qB1, 2);
    BARRIER();
  }

  // ---- 16 K-steps, fully unrolled; P/Q alternate as the write/load set
  #pragma unroll
  for (int tt = 0; tt < 8; ++tt){
    STEP(2*tt,   (0), pA0,pA1,pB0,pB1);
    STEP(2*tt+1, (1), qA0,qA1,qB0,qB1);
  }

#undef STEP
#undef BARRIER
#undef WRITE_T
#undef LOAD_T

  // epilogue 1: C store. C/D map col=lane&15, row=(lane>>4)*4+reg
  #pragma unroll
  for (int i=0;i<2;i++){
    #pragma unroll
    for (int r=0;r<4;r++){
      int row = row0 + wx*32 + i*16 + fkq*4 + r;
      if (row < M){
        #pragma unroll
        for (int j=0;j<4;j++)
          Cb[(size_t)row*256 + col0 + wy*64 + j*16 + li] = f2bf(acc[i][j][r]);
      }
    }
  }

  // epilogue 2: fused att1 dots for head hw (this wave's 64-col span)
  const int hw = (int)blockIdx.y*2 + wy;
  float sv[4], dv[4];
  #pragma unroll
  for (int j=0;j<4;j++){
    sv[j] = SW[hw*64 + j*16 + li];
    dv[j] = DW[hw*64 + j*16 + li];
  }
  #pragma unroll
  for (int i=0;i<2;i++){
    #pragma unroll
    for (int r=0;r<4;r++){
      float ps = acc[i][0][r]*sv[0] + acc[i][1][r]*sv[1] + acc[i][2][r]*sv[2] + acc[i][3][r]*sv[3];
      float pd = acc[i][0][r]*dv[0] + acc[i][1][r]*dv[1] + acc[i][2][r]*dv[2] + acc[i][3][r]*dv[3];
      #pragma unroll
      for (int o=1;o<16;o<<=1){ ps += __shfl_xor(ps,o); pd += __shfl_xor(pd,o); }
      int row = row0 + wx*32 + i*16 + fkq*4 + r;
      if (li == 0 && row < M){
        as1[row*4 + hw] = ps;
        ad1[row*4 + hw] = pd;
      }
    }
  }
}

// ---------------- scatter edges into CSR + compute per-edge ex (4 heads) ----------
__global__ void k_fill(const int* __restrict__ ei, int E, int n,
                       const int* __restrict__ rowstart, int* __restrict__ cur,
                       int* __restrict__ csr,
                       const float* __restrict__ as1, const float* __restrict__ ad1,
                       float* __restrict__ exbuf){
  int i = blockIdx.x*blockDim.x + threadIdx.x;
  int tot = E + n;
  if (i >= tot) return;
  int src, dst;
  if (i < E){ src = ei[i]; dst = ei[E+i]; } else { src = i - E; dst = src; }
  int pos = atomicAdd(&cur[dst], 1);
  int slot = rowstart[dst] + pos;
  csr[slot] = src;
  float4 a = *(const float4*)(as1 + (size_t)src*4);
  float4 d = *(const float4*)(ad1 + (size_t)dst*4);
  float4 ex;
  ex.x = __expf(fminf(leaky(a.x + d.x), 80.f));
  ex.y = __expf(fminf(leaky(a.y + d.y), 80.f));
  ex.z = __expf(fminf(leaky(a.z + d.z), 80.f));
  ex.w = __expf(fminf(leaky(a.w + d.w), 80.f));
  *(float4*)(exbuf + (size_t)slot*4) = ex;
}

// ---------------- aggregation L1: pure gather+fma, denom inline, + bias + ELU ----------
__global__ __launch_bounds__(256) void k_agg1(const unsigned short* __restrict__ h1b,
    const float* __restrict__ exbuf,
    const int* __restrict__ rowstart, const int* __restrict__ csr,
    const float* __restrict__ b1, unsigned short* __restrict__ hactb, int n){
  int lane = threadIdx.x & 63;
  int node = blockIdx.x*4 + (threadIdx.x >> 6);
  if (node >= n) return;
  int lo = __builtin_amdgcn_readfirstlane(rowstart[node]);
  int hi = __builtin_amdgcn_readfirstlane(rowstart[node+1]);
  int h = lane >> 4;
  const float* exb = exbuf + h;          // lane reads exbuf[e*4+h]
  float ax=0.f, ay=0.f, az=0.f, aw=0.f, psum=0.f;
  int e = lo;
  for (; e + 7 < hi; e += 8){
    int s0 = csr[e],   s1 = csr[e+1], s2 = csr[e+2], s3 = csr[e+3];   // scalar
    int s4 = csr[e+4], s5 = csr[e+5], s6 = csr[e+6], s7 = csr[e+7];
    float e0 = exb[(size_t)e*4],     e1 = exb[(size_t)(e+1)*4],
          e2 = exb[(size_t)(e+2)*4], e3 = exb[(size_t)(e+3)*4],
          e4 = exb[(size_t)(e+4)*4], e5 = exb[(size_t)(e+5)*4],
          e6 = exb[(size_t)(e+6)*4], e7 = exb[(size_t)(e+7)*4];
    ushort4 u0 = *(const ushort4*)(h1b + (size_t)s0*256 + lane*4);
    ushort4 u1 = *(const ushort4*)(h1b + (size_t)s1*256 + lane*4);
    ushort4 u2 = *(const ushort4*)(h1b + (size_t)s2*256 + lane*4);
    ushort4 u3 = *(const ushort4*)(h1b + (size_t)s3*256 + lane*4);
    ushort4 u4 = *(const ushort4*)(h1b + (size_t)s4*256 + lane*4);
    ushort4 u5 = *(const ushort4*)(h1b + (size_t)s5*256 + lane*4);
    ushort4 u6 = *(const ushort4*)(h1b + (size_t)s6*256 + lane*4);
    ushort4 u7 = *(const ushort4*)(h1b + (size_t)s7*256 + lane*4);
    ax += e0*bf2f(u0.x) + e1*bf2f(u1.x) + e2*bf2f(u2.x) + e3*bf2f(u3.x)
        + e4*bf2f(u4.x) + e5*bf2f(u5.x) + e6*bf2f(u6.x) + e7*bf2f(u7.x);
    ay += e0*bf2f(u0.y) + e1*bf2f(u1.y) + e2*bf2f(u2.y) + e3*bf2f(u3.y)
        + e4*bf2f(u4.y) + e5*bf2f(u5.y) + e6*bf2f(u6.y) + e7*bf2f(u7.y);
    az += e0*bf2f(u0.z) + e1*bf2f(u1.z) + e2*bf2f(u2.z) + e3*bf2f(u3.z)
        + e4*bf2f(u4.z) + e5*bf2f(u5.z) + e6*bf2f(u6.z) + e7*bf2f(u7.z);
    aw += e0*bf2f(u0.w) + e1*bf2f(u1.w) + e2*bf2f(u2.w) + e3*bf2f(u3.w)
        + e4*bf2f(u4.w) + e5*bf2f(u5.w) + e6*bf2f(u6.w) + e7*bf2f(u7.w);
    psum += (e0+e1+e2+e3) + (e4+e5+e6+e7);
  }
  for (; e < hi; ++e){
    int s0 = csr[e];
    float e0 = exb[(size_t)e*4];
    ushort4 u0 = *(const ushort4*)(h1b + (size_t)s0*256 + lane*4);
    ax += e0*bf2f(u0.x); ay += e0*bf2f(u0.y); az += e0*bf2f(u0.z); aw += e0*bf2f(u0.w);
    psum += e0;
  }
  float inv = 1.f/(psum + 1e-16f);
  float4 bv = *(const float4*)(b1 + lane*4);
  float o0 = ax*inv + bv.x, o1 = ay*inv + bv.y, o2 = az*inv + bv.z, o3 = aw*inv + bv.w;
  ushort4 r;
  r.x = f2bf(o0 > 0.f ? o0 : expm1f(o0));
  r.y = f2bf(o1 > 0.f ? o1 : expm1f(o1));
  r.z = f2bf(o2 > 0.f ? o2 : expm1f(o2));
  r.w = f2bf(o3 > 0.f ? o3 : expm1f(o3));
  *(ushort4*)(hactb + (size_t)node*256 + lane*4) = r;
}

// ---------------- GEMM2: hact[M,256]bf16 @ W2[256,40]f32 -> h2b[M,40]bf16 ------------
// + fused att2: as2/ad2 [N] via LDS reduce.
__global__ __launch_bounds__(256) void k_gemm2(const unsigned short* __restrict__ A,
    const float* __restrict__ B, const float* __restrict__ sw, const float* __restrict__ dw,
    unsigned short* __restrict__ Cb, float* __restrict__ as2, float* __restrict__ ad2, int M){
  __shared__ float Xl[32][129];       // pad -> conflict-free column reads
  __shared__ float Wl[128*40];
  __shared__ float Sps[32][8], Spd[32][8];
  int t = threadIdx.x;
  int row0 = blockIdx.x*32;
  int r = t & 31, g = t >> 5;         // g in 0..7 -> cols g*5 .. g*5+4
  float acc[5] = {0,0,0,0,0};
  for (int kt=0; kt<256; kt+=128){
    for (int i=t; i<1280; i+=256)
      *(float4*)&Wl[i*4] = *(const float4*)(B + kt*40 + i*4);
    for (int i=t; i<512; i+=256){     // 32 rows x 128 k, 8 bf16 per chunk
      int rr = i >> 4, k8 = i & 15;
      int grow = row0 + rr; if (grow >= M) grow = M-1;
      uint4 v = *(const uint4*)(A + (size_t)grow*256 + kt + k8*8);
      float* xp = &Xl[rr][k8*8];
      xp[0] = __uint_as_float(v.x << 16); xp[1] = __uint_as_float(v.x & 0xffff0000u);
      xp[2] = __uint_as_float(v.y << 16); xp[3] = __uint_as_float(v.y & 0xffff0000u);
      xp[4] = __uint_as_float(v.z << 16); xp[5] = __uint_as_float(v.z & 0xffff0000u);
      xp[6] = __uint_as_float(v.w << 16); xp[7] = __uint_as_float(v.w & 0xffff0000u);
    }
    __syncthreads();
    #pragma unroll 4
    for (int k=0;k<128;++k){
      float a = Xl[r][k];
      const float* wp = &Wl[k*40 + g*5];
      #pragma unroll
      for (int j=0;j<5;++j) acc[j] += a * wp[j];
    }
    __syncthreads();
  }
  int grow = row0 + r;
  float ps = 0.f, pd = 0.f;
  #pragma unroll
  for (int j=0;j<5;++j){
    ps += acc[j] * sw[g*5+j];
    pd += acc[j] * dw[g*5+j];
  }
  Sps[r][g] = ps; Spd[r][g] = pd;
  if (grow < M){
    #pragma unroll
    for (int j=0;j<5;++j) Cb[(size_t)grow*40 + g*5 + j] = f2bf(acc[j]);
  }
  __syncthreads();
  if (t < 32){
    float a = 0.f, b = 0.f;
    #pragma unroll
    for (int g2=0; g2<8; ++g2){ a += Sps[t][g2]; b += Spd[t][g2]; }
    int rw = row0 + t;
    if (rw < M){ as2[rw] = a; ad2[rw] = b; }
  }
}

// ---------------- pre-pass L2: per-edge ex (no max, single pass) ----------------
__global__ __launch_bounds__(256) void k_pre2(const float* __restrict__ as2,
    const float* __restrict__ ad2, const int* __restrict__ rowstart,
    const int* __restrict__ csr, float* __restrict__ ex2, int n){
  int lane = threadIdx.x & 63;
  int node = blockIdx.x*4 + (threadIdx.x >> 6);
  if (node >= n) return;
  int lo = rowstart[node], hi = rowstart[node+1];
  float adn = ad2[node];
  for (int e = lo + lane; e < hi; e += 64)
    ex2[e] = __expf(fminf(leaky(as2[csr[e]] + adn), 80.f));
}

// ---------------- aggregation L2: gather+fma, denom inline, + bias + log_softmax ------
__global__ __launch_bounds__(256) void k_agg2(const unsigned short* __restrict__ h2b,
    const float* __restrict__ ex2,
    const int* __restrict__ rowstart, const int* __restrict__ csr,
    const float* __restrict__ b2, float* __restrict__ out, int n){
  int lane = threadIdx.x & 63;
  int node = blockIdx.x*4 + (threadIdx.x >> 6);
  if (node >= n) return;
  int lo = __builtin_amdgcn_readfirstlane(rowstart[node]);
  int hi = __builtin_amdgcn_readfirstlane(rowstart[node+1]);
  bool act = lane < 40;
  float acc = 0.f, psum = 0.f;
  int e = lo;
  for (; e + 7 < hi; e += 8){
    int s0 = csr[e],   s1 = csr[e+1], s2 = csr[e+2], s3 = csr[e+3];   // scalar
    int s4 = csr[e+4], s5 = csr[e+5], s6 = csr[e+6], s7 = csr[e+7];
    float e0 = ex2[e],   e1 = ex2[e+1], e2 = ex2[e+2], e3 = ex2[e+3]; // scalar
    float e4 = ex2[e+4], e5 = ex2[e+5], e6 = ex2[e+6], e7 = ex2[e+7];
    float h0 = act ? bf2f(h2b[(size_t)s0*40 + lane]) : 0.f;
    float h1 = act ? bf2f(h2b[(size_t)s1*40 + lane]) : 0.f;
    float h2 = act ? bf2f(h2b[(size_t)s2*40 + lane]) : 0.f;
    float h3 = act ? bf2f(h2b[(size_t)s3*40 + lane]) : 0.f;
    float h4 = act ? bf2f(h2b[(size_t)s4*40 + lane]) : 0.f;
    float h5 = act ? bf2f(h2b[(size_t)s5*40 + lane]) : 0.f;
    float h6 = act ? bf2f(h2b[(size_t)s6*40 + lane]) : 0.f;
    float h7 = act ? bf2f(h2b[(size_t)s7*40 + lane]) : 0.f;
    acc += e0*h0 + e1*h1 + e2*h2 + e3*h3 + e4*h4 + e5*h5 + e6*h6 + e7*h7;
    psum += (e0+e1+e2+e3) + (e4+e5+e6+e7);
  }
  for (; e < hi; ++e){
    int s0 = csr[e]; float e0 = ex2[e];
    acc += e0 * (act ? bf2f(h2b[(size_t)s0*40 + lane]) : 0.f);
    psum += e0;
  }
  float ov = acc/(psum + 1e-16f) + (act ? b2[lane] : 0.f);
  float v = act ? ov : -INFINITY;
  float mx = v;
  #pragma unroll
  for (int o=1;o<64;o<<=1) mx = fmaxf(mx, __shfl_xor(mx,o));
  float ev = act ? __expf(ov - mx) : 0.f;
  float se = ev;
  #pragma unroll
  for (int o=1;o<64;o<<=1) se += __shfl_xor(se,o);
  if (act) out[(size_t)node*40 + lane] = (ov - mx) - __logf(se);
}

extern "C" void kernel_launch(void* const* d_in, const int* in_sizes, int n_in,
                              void* d_out, int out_size, void* d_ws, size_t ws_size,
                              hipStream_t stream){
  const float* x   = (const float*)d_in[0];
  const int*   ei  = (const int*)d_in[1];     // [2,E] int32 (harness contract)
  const float* W1  = (const float*)d_in[2];
  const float* s1w = (const float*)d_in[3];
  const float* d1w = (const float*)d_in[4];
  const float* b1  = (const float*)d_in[5];
  const float* W2  = (const float*)d_in[6];
  const float* s2w = (const float*)d_in[7];
  const float* d2w = (const float*)d_in[8];
  const float* b2  = (const float*)d_in[9];
  float* out = (float*)d_out;

  const int N  = in_sizes[0] / 512;
  const int E  = in_sizes[1] / 2;
  const int Et = E + N;

  // workspace carve-out (~80 MB)
  float* f = (float*)d_ws;
  unsigned short* h1b   = (unsigned short*)f;  f += (size_t)N*128;   // [N][256] bf16
  unsigned short* hactb = (unsigned short*)f;  f += (size_t)N*128;   // [N][256] bf16
  float* as1  = f;  f += (size_t)N*4;
  float* ad1  = f;  f += (size_t)N*4;
  float* as2  = f;  f += N;
  float* ad2  = f;  f += N;
  unsigned short* w1t = (unsigned short*)f;  f += 256*512/2;         // [kt][kq][col][8] bf16
  unsigned short* h2b = (unsigned short*)f;  f += (size_t)N*40/2 + 64; // [N][40] bf16
  float* exbuf = f;  f += (size_t)Et*4;                              // [Et][4] f32
  float* ex2   = f;  f += Et;                                        // [Et] f32
  int* ip = (int*)f;
  int* rowstart = ip;  ip += (N + 4) & ~3;
  int* deg      = ip;  ip += N;
  int* cur      = ip;  ip += N;
  int* csr      = ip;  ip += Et;
  int* bsum     = ip;  ip += 256;

  int nb4 = (N + 3) / 4;
  int nbs = (N + 255) / 256;                 // scan blocks (196 <= 256)
  k_cvt_w<<<nbs, 256, 0, stream>>>(W1, w1t, deg, N);
  k_count<<<(Et+255)/256, 256, 0, stream>>>(ei, E, N, deg);
  k_scan_a<<<nbs, 256, 0, stream>>>(deg, rowstart, bsum, N);
  k_scan_b<<<1, 256, 0, stream>>>(bsum, nbs);
  k_scan_c<<<nbs, 256, 0, stream>>>(rowstart, bsum, cur, N);
  k_gemm1_mfma<<<dim3((N+63)/64, 2), 256, 0, stream>>>(x, w1t, s1w, d1w, h1b, as1, ad1, N);
  k_fill <<<(Et+255)/256, 256, 0, stream>>>(ei, E, N, rowstart, cur, csr, as1, ad1, exbuf);
  k_agg1 <<<nb4, 256, 0, stream>>>(h1b, exbuf, rowstart, csr, b1, hactb, N);
  k_gemm2<<<(N+31)/32, 256, 0, stream>>>(hactb, W2, s2w, d2w, h2b, as2, ad2, N);
  k_pre2 <<<nb4, 256, 0, stream>>>(as2, ad2, rowstart, csr, ex2, N);
  k_agg2 <<<nb4, 256, 0, stream>>>(h2b, ex2, rowstart, csr, b2, out, N);
}